// Round 11
// baseline (297.465 us; speedup 1.0000x reference)
//
#include <hip/hip_runtime.h>
#include <hip/hip_bf16.h>

#define NN 100000
#define NE 1600000
#define NF 128
#define NH 64
#define NC 16
#define NB1 391    // ceil(NN/256)
#define GBIN 256   // binning workgroups
#define CHUNK 6250 // NE/GBIN
#define BBUK 196   // ceil(NN/512) coarse buckets of 512 nodes
#define NCB 196    // 256-blocks per counts array (BBUK*GBIN/256)
#define NGRP 1563  // ceil(NN/64) gemm1 row-groups

typedef __attribute__((ext_vector_type(8))) short short8v;
typedef __attribute__((ext_vector_type(4))) float float4v;

__device__ __forceinline__ float us2f(unsigned short u) {
    return __uint_as_float(((unsigned int)u) << 16);
}
__device__ __forceinline__ unsigned short f2us_rn(float f) {
    unsigned int u = __float_as_uint(f);
    return (unsigned short)((u + 0x7FFFu + ((u >> 16) & 1u)) >> 16);
}
__device__ __forceinline__ float ldf(const void* p, size_t i, bool f32) {
    return f32 ? ((const float*)p)[i] : us2f(((const unsigned short*)p)[i]);
}

// ---------------- dtype sniff (validated R2; live mode=1/fp32 per R9) ----------------
__global__ void k_sniff(const unsigned short* __restrict__ xu, int* __restrict__ mode) {
    __shared__ int cnt;
    if (threadIdx.x == 0) cnt = 0;
    __syncthreads();
    int c = 0;
    for (int i = threadIdx.x; i < 4096; i += 256) {
        unsigned int e = (xu[i] >> 7) & 0xFFu;
        if (e >= 160u) c++;
    }
    atomicAdd(&cnt, c);
    __syncthreads();
    if (threadIdx.x == 0) mode[0] = (cnt >= 16) ? 1 : 0;
}

// ---------------- fallback path kernels (global atomics) ----------------
__global__ void k_deg(const int4* __restrict__ src4, const int4* __restrict__ dst4,
                      int* __restrict__ deg_out, int* __restrict__ deg_in) {
    int i = blockIdx.x * blockDim.x + threadIdx.x;
    if (i < NE / 4) {
        int4 s = src4[i], d = dst4[i];
        atomicAdd(&deg_out[s.x], 1); atomicAdd(&deg_out[s.y], 1);
        atomicAdd(&deg_out[s.z], 1); atomicAdd(&deg_out[s.w], 1);
        atomicAdd(&deg_in[d.x], 1);  atomicAdd(&deg_in[d.y], 1);
        atomicAdd(&deg_in[d.z], 1);  atomicAdd(&deg_in[d.w], 1);
    }
}

__global__ void k_scatter(const int* __restrict__ src, const int* __restrict__ dst,
                          int* __restrict__ cursor, int* __restrict__ srcs_sorted) {
    int e = blockIdx.x * blockDim.x + threadIdx.x;
    if (e < NE) {
        int p = atomicAdd(&cursor[dst[e]], 1);
        srcs_sorted[p] = src[e];
    }
}

// ---------------- fast CSR 1: per-(bucket,group) histograms of dst AND src ----------------
__global__ __launch_bounds__(256) void k_hist2(const int* __restrict__ src,
                                               const int* __restrict__ dst,
                                               int* __restrict__ counts_d,
                                               int* __restrict__ counts_s) {
    __shared__ int hd[BBUK], hs[BBUK];
    for (int i = threadIdx.x; i < BBUK; i += 256) { hd[i] = 0; hs[i] = 0; }
    __syncthreads();
    const int g = blockIdx.x;
    const int e0 = g * CHUNK;
    for (int i = threadIdx.x; i < CHUNK; i += 256) {
        atomicAdd(&hd[dst[e0 + i] >> 9], 1);
        atomicAdd(&hs[src[e0 + i] >> 9], 1);
    }
    __syncthreads();
    for (int i = threadIdx.x; i < BBUK; i += 256) {
        counts_d[i * GBIN + g] = hd[i];
        counts_s[i * GBIN + g] = hs[i];
    }
}

// ---------------- fast CSR 2: fused exclusive scan of both counts arrays ----------------
__global__ void k_cs_a(const int* __restrict__ counts, int* __restrict__ csum) {
    __shared__ int s[256];
    int i = blockIdx.x * 256 + threadIdx.x;
    s[threadIdx.x] = counts[i];
    __syncthreads();
    for (int off = 128; off > 0; off >>= 1) {
        if (threadIdx.x < off) s[threadIdx.x] += s[threadIdx.x + off];
        __syncthreads();
    }
    if (threadIdx.x == 0) csum[blockIdx.x] = s[0];
}

__global__ void k_cs_b2(const int* __restrict__ csum, int* __restrict__ coff) {
    __shared__ int s[512];
    int t = threadIdx.x;
    int half = t >> 8, j = t & 255;
    s[t] = (j < NCB) ? csum[half * NCB + j] : 0;
    __syncthreads();
    for (int off = 1; off < 256; off <<= 1) {
        int v = (j >= off) ? s[t - off] : 0;
        __syncthreads();
        s[t] += v;
        __syncthreads();
    }
    if (j < NCB) coff[half * NCB + j] = (j == 0) ? 0 : s[t - 1];
}

__global__ void k_cs_c(int* __restrict__ counts, const int* __restrict__ coff) {
    __shared__ int s[256];
    int t = threadIdx.x;
    int i = blockIdx.x * 256 + t;
    int v = counts[i];
    s[t] = v;
    __syncthreads();
    for (int off = 1; off < 256; off <<= 1) {
        int u = (t >= off) ? s[t - off] : 0;
        __syncthreads();
        s[t] += u;
        __syncthreads();
    }
    counts[i] = s[t] - v + coff[blockIdx.x];
}

// ---------------- fast CSR 3: private-slice binning of dst-edges AND src-residues ----------------
__global__ __launch_bounds__(256) void k_binscatter2(const int* __restrict__ src,
                                                     const int* __restrict__ dst,
                                                     const int* __restrict__ counts_d,
                                                     const int* __restrict__ counts_s,
                                                     unsigned int* __restrict__ packed,
                                                     unsigned short* __restrict__ packed2) {
    __shared__ int curd[BBUK], curs[BBUK];
    const int g = blockIdx.x;
    for (int i = threadIdx.x; i < BBUK; i += 256) {
        curd[i] = counts_d[i * GBIN + g];
        curs[i] = counts_s[i * GBIN + g];
    }
    __syncthreads();
    const int e0 = g * CHUNK;
    for (int i = threadIdx.x; i < CHUNK; i += 256) {
        int s = src[e0 + i], d = dst[e0 + i];
        int pd = atomicAdd(&curd[d >> 9], 1);
        packed[pd] = ((unsigned)s << 9) | (unsigned)(d & 511);
        int ps = atomicAdd(&curs[s >> 9], 1);
        packed2[ps] = (unsigned short)(s & 511);
    }
}

// ---------------- fast CSR 4: per-bucket LDS degree histograms ----------------
__global__ __launch_bounds__(256) void k_bdeg_in(const int* __restrict__ counts_d,
                                                 const unsigned int* __restrict__ packed,
                                                 int* __restrict__ deg_in) {
    __shared__ int h[512];
    const int b = blockIdx.x;
    const int n0 = b << 9;
    const int nlim = (NN - n0 < 512) ? (NN - n0) : 512;
    for (int j = threadIdx.x; j < 512; j += 256) h[j] = 0;
    __syncthreads();
    const int beg = counts_d[b * GBIN];
    const int end = (b + 1 < BBUK) ? counts_d[(b + 1) * GBIN] : NE;
    for (int i = beg + threadIdx.x; i < end; i += 256)
        atomicAdd(&h[packed[i] & 511u], 1);
    __syncthreads();
    for (int j = threadIdx.x; j < nlim; j += 256) deg_in[n0 + j] = h[j];
}

__global__ __launch_bounds__(256) void k_bdeg_out(const int* __restrict__ counts_s,
                                                  const unsigned short* __restrict__ packed2,
                                                  int* __restrict__ deg_out) {
    __shared__ int h[512];
    const int b = blockIdx.x;
    const int n0 = b << 9;
    const int nlim = (NN - n0 < 512) ? (NN - n0) : 512;
    for (int j = threadIdx.x; j < 512; j += 256) h[j] = 0;
    __syncthreads();
    const int beg = counts_s[b * GBIN];
    const int end = (b + 1 < BBUK) ? counts_s[(b + 1) * GBIN] : NE;
    for (int i = beg + threadIdx.x; i < end; i += 256)
        atomicAdd(&h[packed2[i] & 511u], 1);
    __syncthreads();
    for (int j = threadIdx.x; j < nlim; j += 256) deg_out[n0 + j] = h[j];
}

// ---------------- node-level scan -> row_off, cursors, norms ----------------
__global__ void k_scan_a(const int* __restrict__ deg_in, int* __restrict__ bsum) {
    __shared__ int s[256];
    int i = blockIdx.x * 256 + threadIdx.x;
    s[threadIdx.x] = (i < NN) ? deg_in[i] : 0;
    __syncthreads();
    for (int off = 128; off > 0; off >>= 1) {
        if (threadIdx.x < off) s[threadIdx.x] += s[threadIdx.x + off];
        __syncthreads();
    }
    if (threadIdx.x == 0) bsum[blockIdx.x] = s[0];
}

__global__ void k_scan_b(const int* __restrict__ bsum, int* __restrict__ boff) {
    __shared__ int s[512];
    int t = threadIdx.x;
    s[t] = (t < NB1) ? bsum[t] : 0;
    __syncthreads();
    for (int off = 1; off < 512; off <<= 1) {
        int v = (t >= off) ? s[t - off] : 0;
        __syncthreads();
        s[t] += v;
        __syncthreads();
    }
    if (t < NB1) boff[t] = (t == 0) ? 0 : s[t - 1];
}

__global__ void k_scan_c(const int* __restrict__ deg_in, const int* __restrict__ deg_out,
                         const int* __restrict__ boff, int* __restrict__ row_off,
                         int* __restrict__ cursor, float* __restrict__ nsrc,
                         float* __restrict__ ndst) {
    __shared__ int s[256];
    int t = threadIdx.x;
    int i = blockIdx.x * 256 + t;
    int d = (i < NN) ? deg_in[i] : 0;
    s[t] = d;
    __syncthreads();
    for (int off = 1; off < 256; off <<= 1) {
        int v = (t >= off) ? s[t - off] : 0;
        __syncthreads();
        s[t] += v;
        __syncthreads();
    }
    int excl = s[t] - d + boff[blockIdx.x];
    if (i < NN) {
        row_off[i] = excl;
        cursor[i]  = excl;
        ndst[i] = rsqrtf(fmaxf((float)d, 1.0f));
        nsrc[i] = rsqrtf(fmaxf((float)deg_out[i], 1.0f));
        if (i == NN - 1) row_off[NN] = excl + d;
    }
}

// ---------------- fast CSR 5: within-bucket scatter via LDS cursors ----------------
__global__ __launch_bounds__(256) void k_bucketC512(const int* __restrict__ row_off,
                                                    const unsigned int* __restrict__ packed,
                                                    int* __restrict__ srcs_sorted) {
    __shared__ int lcur[512];
    const int n0 = blockIdx.x << 9;
    const int nlim = (NN - n0 < 512) ? (NN - n0) : 512;
    for (int j = threadIdx.x; j < 512; j += 256)
        lcur[j] = (j < nlim) ? row_off[n0 + j] : 0;
    __syncthreads();
    const int beg = row_off[n0];
    const int end = row_off[n0 + nlim];
    for (int i = beg + threadIdx.x; i < end; i += 256) {
        unsigned v = packed[i];
        int p = atomicAdd(&lcur[v & 511u], 1);
        srcs_sorted[p] = (int)(v >> 9);
    }
}

// ---------------- W1 -> bf16 fragment-ordered layout ----------------
__global__ void k_prepW(const void* __restrict__ W1, unsigned short* __restrict__ W1f,
                        const int* __restrict__ mode) {
    const bool f32 = (mode[0] != 0);
    for (int i = threadIdx.x; i < 1024; i += 256) {
        const int kcnt = i >> 6, lane = i & 63;
        const int kc = kcnt >> 2, nt = kcnt & 3;
        const int quad = lane >> 4, col = lane & 15;
        #pragma unroll
        for (int j = 0; j < 8; ++j) {
            const size_t idx = (size_t)(kc * 32 + quad * 8 + j) * NH + nt * 16 + col;
            W1f[(size_t)i * 8 + j] = f32 ? f2us_rn(((const float*)W1)[idx])
                                         : ((const unsigned short*)W1)[idx];
        }
    }
}

// ---------------- layer 1 GEMM (MFMA, both dtypes) ----------------
__global__ __launch_bounds__(256) void k_gemm1_mfma(
    const void* __restrict__ x, const unsigned short* __restrict__ W1f,
    const float* __restrict__ nsrc, unsigned short* __restrict__ h1,
    const int* __restrict__ mode)
{
    const bool f32 = (mode[0] != 0);
    const int tid = threadIdx.x;
    const int wave = tid >> 6, lane = tid & 63;
    const int col = lane & 15, quad = lane >> 4;

    short8v bfrag[16];
    #pragma unroll
    for (int f = 0; f < 16; ++f)
        bfrag[f] = *(const short8v*)(W1f + ((size_t)f * 64 + lane) * 8);

    const int base = blockIdx.x * 64 + wave * 16;
    int arow = base + col;
    if (arow > NN - 1) arow = NN - 1;

    short8v afrag[4];
    if (f32) {
        const float4* ap = (const float4*)((const float*)x + (size_t)arow * NF);
        #pragma unroll
        for (int kc = 0; kc < 4; ++kc) {
            float4 v0 = ap[kc * 8 + quad * 2];
            float4 v1 = ap[kc * 8 + quad * 2 + 1];
            short8v af;
            af[0] = (short)f2us_rn(v0.x); af[1] = (short)f2us_rn(v0.y);
            af[2] = (short)f2us_rn(v0.z); af[3] = (short)f2us_rn(v0.w);
            af[4] = (short)f2us_rn(v1.x); af[5] = (short)f2us_rn(v1.y);
            af[6] = (short)f2us_rn(v1.z); af[7] = (short)f2us_rn(v1.w);
            afrag[kc] = af;
        }
    } else {
        const uint4* ap = (const uint4*)((const unsigned short*)x + (size_t)arow * NF);
        #pragma unroll
        for (int kc = 0; kc < 4; ++kc) {
            uint4 v = ap[kc * 4 + quad];
            afrag[kc] = *reinterpret_cast<const short8v*>(&v);
        }
    }

    float4v acc[4];
    #pragma unroll
    for (int nt = 0; nt < 4; ++nt) acc[nt] = (float4v){0.f, 0.f, 0.f, 0.f};
    #pragma unroll
    for (int kc = 0; kc < 4; ++kc)
        #pragma unroll
        for (int nt = 0; nt < 4; ++nt)
            acc[nt] = __builtin_amdgcn_mfma_f32_16x16x32_bf16(afrag[kc], bfrag[kc * 4 + nt], acc[nt], 0, 0, 0);

    #pragma unroll
    for (int reg = 0; reg < 4; ++reg) {
        const int row = base + quad * 4 + reg;
        if (row < NN) {
            const float ns = nsrc[row];
            unsigned short* hp = h1 + (size_t)row * NH + col;
            hp[0]  = f2us_rn(acc[0][reg] * ns);
            hp[16] = f2us_rn(acc[1][reg] * ns);
            hp[32] = f2us_rn(acc[2][reg] * ns);
            hp[48] = f2us_rn(acc[3][reg] * ns);
        }
    }
}

// ---------------- fused layer-1 aggregation + relu + W2 GEMM ----------------
// 8 edge slots (q) x 8 feature-octs (li); dwordx4 gathers (16 B/lane), 2-deep.
// Lane (q,li) computes W2 partials for cols {q, q+8}; xor-reduce over li.
__global__ __launch_bounds__(256) void k_agg1csr(
    const int* __restrict__ row_off, const int* __restrict__ srcs,
    const unsigned short* __restrict__ h1, const float* __restrict__ ndst,
    const float* __restrict__ nsrc, const void* __restrict__ b1,
    const void* __restrict__ W2, const int* __restrict__ mode,
    unsigned short* __restrict__ h2)
{
    const bool f32 = (mode[0] != 0);
    const int lane = threadIdx.x & 63;
    const int q  = lane >> 3;    // slot / output col subset {q, q+8}
    const int li = lane & 7;     // feature oct: feats 8li..8li+7

    float bias[8], w2a[8], w2b[8];
    #pragma unroll
    for (int j = 0; j < 8; ++j) {
        bias[j] = ldf(b1, 8*li+j, f32);
        w2a[j]  = ldf(W2, (size_t)(8*li+j)*NC + q, f32);
        w2b[j]  = ldf(W2, (size_t)(8*li+j)*NC + q + 8, f32);
    }

    const int wid = (blockIdx.x * blockDim.x + threadIdx.x) >> 6;
    const int nw  = (gridDim.x * blockDim.x) >> 6;

    for (int row = wid; row < NN; row += nw) {
        const int beg = row_off[row], end = row_off[row + 1];
        float a0=0.f,a1=0.f,a2=0.f,a3=0.f,a4=0.f,a5=0.f,a6=0.f,a7=0.f;
        float c0=0.f,c1=0.f,c2=0.f,c3=0.f,c4=0.f,c5=0.f,c6=0.f,c7=0.f;
        int i = beg + q;
        int s0 = (i     < end) ? srcs[i]     : 0;
        int s1 = (i + 8 < end) ? srcs[i + 8] : 0;
        while (i + 8 < end) {
            uint4 v0 = *(const uint4*)(h1 + (size_t)s0 * NH + 8*li);
            uint4 v1 = *(const uint4*)(h1 + (size_t)s1 * NH + 8*li);
            const int inext = i + 16;
            s0 = (inext     < end) ? srcs[inext]     : 0;
            s1 = (inext + 8 < end) ? srcs[inext + 8] : 0;
            a0 += us2f((unsigned short)(v0.x & 0xFFFF)); a1 += us2f((unsigned short)(v0.x >> 16));
            a2 += us2f((unsigned short)(v0.y & 0xFFFF)); a3 += us2f((unsigned short)(v0.y >> 16));
            a4 += us2f((unsigned short)(v0.z & 0xFFFF)); a5 += us2f((unsigned short)(v0.z >> 16));
            a6 += us2f((unsigned short)(v0.w & 0xFFFF)); a7 += us2f((unsigned short)(v0.w >> 16));
            c0 += us2f((unsigned short)(v1.x & 0xFFFF)); c1 += us2f((unsigned short)(v1.x >> 16));
            c2 += us2f((unsigned short)(v1.y & 0xFFFF)); c3 += us2f((unsigned short)(v1.y >> 16));
            c4 += us2f((unsigned short)(v1.z & 0xFFFF)); c5 += us2f((unsigned short)(v1.z >> 16));
            c6 += us2f((unsigned short)(v1.w & 0xFFFF)); c7 += us2f((unsigned short)(v1.w >> 16));
            i = inext;
        }
        if (i < end) {
            uint4 v0 = *(const uint4*)(h1 + (size_t)s0 * NH + 8*li);
            a0 += us2f((unsigned short)(v0.x & 0xFFFF)); a1 += us2f((unsigned short)(v0.x >> 16));
            a2 += us2f((unsigned short)(v0.y & 0xFFFF)); a3 += us2f((unsigned short)(v0.y >> 16));
            a4 += us2f((unsigned short)(v0.z & 0xFFFF)); a5 += us2f((unsigned short)(v0.z >> 16));
            a6 += us2f((unsigned short)(v0.w & 0xFFFF)); a7 += us2f((unsigned short)(v0.w >> 16));
        }
        a0 += c0; a1 += c1; a2 += c2; a3 += c3;
        a4 += c4; a5 += c5; a6 += c6; a7 += c7;
        // merge 8 slots (xor 8, 16, 32)
        #pragma unroll
        for (int off = 8; off <= 32; off <<= 1) {
            a0 += __shfl_xor(a0, off); a1 += __shfl_xor(a1, off);
            a2 += __shfl_xor(a2, off); a3 += __shfl_xor(a3, off);
            a4 += __shfl_xor(a4, off); a5 += __shfl_xor(a5, off);
            a6 += __shfl_xor(a6, off); a7 += __shfl_xor(a7, off);
        }
        const float nd = ndst[row];
        float t[8];
        t[0] = fmaxf(fmaf(a0, nd, bias[0]), 0.f);
        t[1] = fmaxf(fmaf(a1, nd, bias[1]), 0.f);
        t[2] = fmaxf(fmaf(a2, nd, bias[2]), 0.f);
        t[3] = fmaxf(fmaf(a3, nd, bias[3]), 0.f);
        t[4] = fmaxf(fmaf(a4, nd, bias[4]), 0.f);
        t[5] = fmaxf(fmaf(a5, nd, bias[5]), 0.f);
        t[6] = fmaxf(fmaf(a6, nd, bias[6]), 0.f);
        t[7] = fmaxf(fmaf(a7, nd, bias[7]), 0.f);
        float p0 = 0.f, p1 = 0.f;
        #pragma unroll
        for (int j = 0; j < 8; ++j) {
            p0 = fmaf(t[j], w2a[j], p0);
            p1 = fmaf(t[j], w2b[j], p1);
        }
        // reduce over the 8 li lanes (bits 0..2)
        #pragma unroll
        for (int off = 1; off <= 4; off <<= 1) {
            p0 += __shfl_xor(p0, off);
            p1 += __shfl_xor(p1, off);
        }
        if (li == 0) {
            const float ns = nsrc[row];
            h2[(size_t)row * NC + q]     = f2us_rn(p0 * ns);
            h2[(size_t)row * NC + q + 8] = f2us_rn(p1 * ns);
        }
    }
}

// ---------------- fused layer-2 aggregation + bias + log_softmax ----------------
// 8 edge slots (q) x 8 col-pairs (li): dword gathers (cols 2li, 2li+1), 2-deep.
__global__ __launch_bounds__(256) void k_out(
    const int* __restrict__ row_off, const int* __restrict__ srcs,
    const unsigned short* __restrict__ h2, const float* __restrict__ ndst,
    const void* __restrict__ b2, const int* __restrict__ mode,
    void* __restrict__ out)
{
    const bool f32 = (mode[0] != 0);
    const int lane = threadIdx.x & 63;
    const int q  = lane >> 3;
    const int li = lane & 7;
    const float b2v0 = ldf(b2, 2*li,   f32);
    const float b2v1 = ldf(b2, 2*li+1, f32);

    const int wid = (blockIdx.x * blockDim.x + threadIdx.x) >> 6;
    const int nw  = (gridDim.x * blockDim.x) >> 6;

    for (int r = wid; r < NN; r += nw) {
        const int beg = row_off[r], end = row_off[r + 1];
        float a0 = 0.f, a1 = 0.f, c0 = 0.f, c1 = 0.f;
        int i = beg + q;
        int s0 = (i     < end) ? srcs[i]     : 0;
        int s1 = (i + 8 < end) ? srcs[i + 8] : 0;
        while (i + 8 < end) {
            unsigned u0 = *(const unsigned*)(h2 + (size_t)s0 * NC + 2*li);
            unsigned u1 = *(const unsigned*)(h2 + (size_t)s1 * NC + 2*li);
            const int inext = i + 16;
            s0 = (inext     < end) ? srcs[inext]     : 0;
            s1 = (inext + 8 < end) ? srcs[inext + 8] : 0;
            a0 += us2f((unsigned short)(u0 & 0xFFFF));
            a1 += us2f((unsigned short)(u0 >> 16));
            c0 += us2f((unsigned short)(u1 & 0xFFFF));
            c1 += us2f((unsigned short)(u1 >> 16));
            i = inext;
        }
        if (i < end) {
            unsigned u0 = *(const unsigned*)(h2 + (size_t)s0 * NC + 2*li);
            a0 += us2f((unsigned short)(u0 & 0xFFFF));
            a1 += us2f((unsigned short)(u0 >> 16));
        }
        a0 += c0; a1 += c1;
        #pragma unroll
        for (int off = 8; off <= 32; off <<= 1) {
            a0 += __shfl_xor(a0, off);
            a1 += __shfl_xor(a1, off);
        }
        const float nd = ndst[r];
        float v0 = fmaf(a0, nd, b2v0);
        float v1 = fmaf(a1, nd, b2v1);
        float m = fmaxf(v0, v1);
        #pragma unroll
        for (int off = 1; off <= 4; off <<= 1) m = fmaxf(m, __shfl_xor(m, off));
        float sm = __expf(v0 - m) + __expf(v1 - m);
        #pragma unroll
        for (int off = 1; off <= 4; off <<= 1) sm += __shfl_xor(sm, off);
        const float lsm = __logf(sm);
        const float r0 = v0 - m - lsm, r1 = v1 - m - lsm;
        if (q == 0) {
            if (f32) {
                float2 o; o.x = r0; o.y = r1;
                *(float2*)((float*)out + (size_t)r * NC + 2*li) = o;
            } else {
                unsigned o = ((unsigned)f2us_rn(r1) << 16) | (unsigned)f2us_rn(r0);
                *(unsigned*)((unsigned short*)out + (size_t)r * NC + 2*li) = o;
            }
        }
    }
}

extern "C" void kernel_launch(void* const* d_in, const int* in_sizes, int n_in,
                              void* d_out, int out_size, void* d_ws, size_t ws_size,
                              hipStream_t stream) {
    const void* x  = d_in[0];
    const int* src = (const int*)d_in[1];
    const int* dst = (const int*)d_in[2];
    const void* W1 = d_in[3];
    const void* b1 = d_in[4];
    const void* W2 = d_in[5];
    const void* b2 = d_in[6];

    // ---- workspace layout ----
    char* ws = (char*)d_ws;
    const size_t O_MODE = 0;                     // 1 KB
    const size_t O_W1F  = 1024;                  // fragment-ordered W1 (bf16), 16384 B
    const size_t O_CNT  = O_W1F + 16384;         // counts_d + counts_s = 401408
    const size_t O_CS   = O_CNT  + 401408;       // csum 2048 + coff 2048
    const size_t O_DEG  = O_CS   + 4096;         // 800000
    const size_t O_NSRC = O_DEG  + 800000;
    const size_t O_NDST = O_NSRC + 400000;
    const size_t O_ROW  = O_NDST + 400000;       // (NN+1)*4 padded
    const size_t O_CUR  = O_ROW  + 400128;       // fallback per-node cursors
    const size_t O_BS   = O_CUR  + 400128;       // bsum 2048 + boff 2048
    const size_t O_SRCS = O_BS   + 4096;         // NE*4
    const size_t O_H2   = O_SRCS + 6400000;      // NN*NC*2 bf16
    const size_t O_H1   = O_H2   + 3200000;      // NN*NH*2 bf16 = 12800000
    const size_t NEED = O_H1 + 12800000;         // ~25.2 MB
    const bool fast_csr = ws_size >= NEED;

    int*   mode     = (int*)(ws + O_MODE);
    unsigned short* W1f = (unsigned short*)(ws + O_W1F);
    int*   counts_d = (int*)(ws + O_CNT);
    int*   counts_s = counts_d + BBUK * GBIN;
    int*   csum     = (int*)(ws + O_CS);
    int*   coff     = (int*)(ws + O_CS + 2048);
    int*   deg_out  = (int*)(ws + O_DEG);
    int*   deg_in   = deg_out + NN;
    float* nsrc     = (float*)(ws + O_NSRC);
    float* ndst     = (float*)(ws + O_NDST);
    int*   row_off  = (int*)(ws + O_ROW);
    int*   cursor   = (int*)(ws + O_CUR);
    int*   bsum     = (int*)(ws + O_BS);
    int*   boff     = (int*)(ws + O_BS + 2048);
    int*   srcs_s   = (int*)(ws + O_SRCS);
    unsigned short* h2 = (unsigned short*)(ws + O_H2);
    unsigned short* h1 = (unsigned short*)(ws + O_H1);
    unsigned int*   packed  = (unsigned int*)(ws + O_H1);
    unsigned short* packed2 = (unsigned short*)(ws + O_H1 + 6400000);

    k_sniff<<<1, 256, 0, stream>>>((const unsigned short*)x, mode);
    k_prepW<<<1, 256, 0, stream>>>(W1, W1f, mode);
    if (fast_csr) {
        k_hist2<<<GBIN, 256, 0, stream>>>(src, dst, counts_d, counts_s);
        k_cs_a<<<2 * NCB, 256, 0, stream>>>(counts_d, csum);
        k_cs_b2<<<1, 512, 0, stream>>>(csum, coff);
        k_cs_c<<<2 * NCB, 256, 0, stream>>>(counts_d, coff);
        k_binscatter2<<<GBIN, 256, 0, stream>>>(src, dst, counts_d, counts_s, packed, packed2);
        k_bdeg_in<<<BBUK, 256, 0, stream>>>(counts_d, packed, deg_in);
        k_bdeg_out<<<BBUK, 256, 0, stream>>>(counts_s, packed2, deg_out);
        k_scan_a<<<NB1, 256, 0, stream>>>(deg_in, bsum);
        k_scan_b<<<1, 512, 0, stream>>>(bsum, boff);
        k_scan_c<<<NB1, 256, 0, stream>>>(deg_in, deg_out, boff, row_off, cursor, nsrc, ndst);
        k_bucketC512<<<BBUK, 256, 0, stream>>>(row_off, packed, srcs_s);
    } else {
        hipMemsetAsync(deg_out, 0, 2 * (size_t)NN * sizeof(int), stream);
        k_deg<<<(NE / 4 + 255) / 256, 256, 0, stream>>>((const int4*)src, (const int4*)dst, deg_out, deg_in);
        k_scan_a<<<NB1, 256, 0, stream>>>(deg_in, bsum);
        k_scan_b<<<1, 512, 0, stream>>>(bsum, boff);
        k_scan_c<<<NB1, 256, 0, stream>>>(deg_in, deg_out, boff, row_off, cursor, nsrc, ndst);
        k_scatter<<<(NE + 255) / 256, 256, 0, stream>>>(src, dst, cursor, srcs_s);
    }
    k_gemm1_mfma<<<NGRP, 256, 0, stream>>>(x, W1f, nsrc, h1, mode);
    k_agg1csr<<<2048, 256, 0, stream>>>(row_off, srcs_s, h1, ndst, nsrc, b1, W2, mode, h2);
    k_out<<<2048, 256, 0, stream>>>(row_off, srcs_s, h2, ndst, b2, mode, d_out);
}

// Round 12
// 278.952 us; speedup vs baseline: 1.0664x; 1.0664x over previous
//
#include <hip/hip_runtime.h>
#include <hip/hip_bf16.h>

#define NN 100000
#define NE 1600000
#define NF 128
#define NH 64
#define NC 16
#define NB1 391    // ceil(NN/256)
#define GBIN 256   // binning workgroups
#define CHUNK 6250 // NE/GBIN
#define BBUK 196   // ceil(NN/512) coarse buckets of 512 nodes
#define NCB 196    // 256-blocks per counts array (BBUK*GBIN/256)
#define NGRP 1563  // ceil(NN/64) gemm1 row-groups

typedef __attribute__((ext_vector_type(8))) short short8v;
typedef __attribute__((ext_vector_type(4))) float float4v;

__device__ __forceinline__ float us2f(unsigned short u) {
    return __uint_as_float(((unsigned int)u) << 16);
}
__device__ __forceinline__ unsigned short f2us_rn(float f) {
    unsigned int u = __float_as_uint(f);
    return (unsigned short)((u + 0x7FFFu + ((u >> 16) & 1u)) >> 16);
}
__device__ __forceinline__ float ldf(const void* p, size_t i, bool f32) {
    return f32 ? ((const float*)p)[i] : us2f(((const unsigned short*)p)[i]);
}

// ---------------- dtype sniff (validated R2; live mode=1/fp32 per R9) ----------------
__global__ void k_sniff(const unsigned short* __restrict__ xu, int* __restrict__ mode) {
    __shared__ int cnt;
    if (threadIdx.x == 0) cnt = 0;
    __syncthreads();
    int c = 0;
    for (int i = threadIdx.x; i < 4096; i += 256) {
        unsigned int e = (xu[i] >> 7) & 0xFFu;
        if (e >= 160u) c++;
    }
    atomicAdd(&cnt, c);
    __syncthreads();
    if (threadIdx.x == 0) mode[0] = (cnt >= 16) ? 1 : 0;
}

// ---------------- fallback path kernels (global atomics) ----------------
__global__ void k_deg(const int4* __restrict__ src4, const int4* __restrict__ dst4,
                      int* __restrict__ deg_out, int* __restrict__ deg_in) {
    int i = blockIdx.x * blockDim.x + threadIdx.x;
    if (i < NE / 4) {
        int4 s = src4[i], d = dst4[i];
        atomicAdd(&deg_out[s.x], 1); atomicAdd(&deg_out[s.y], 1);
        atomicAdd(&deg_out[s.z], 1); atomicAdd(&deg_out[s.w], 1);
        atomicAdd(&deg_in[d.x], 1);  atomicAdd(&deg_in[d.y], 1);
        atomicAdd(&deg_in[d.z], 1);  atomicAdd(&deg_in[d.w], 1);
    }
}

__global__ void k_scatter(const int* __restrict__ src, const int* __restrict__ dst,
                          int* __restrict__ cursor, int* __restrict__ srcs_sorted) {
    int e = blockIdx.x * blockDim.x + threadIdx.x;
    if (e < NE) {
        int p = atomicAdd(&cursor[dst[e]], 1);
        srcs_sorted[p] = src[e];
    }
}

__global__ void k_scan_a(const int* __restrict__ deg_in, int* __restrict__ bsum) {
    __shared__ int s[256];
    int i = blockIdx.x * 256 + threadIdx.x;
    s[threadIdx.x] = (i < NN) ? deg_in[i] : 0;
    __syncthreads();
    for (int off = 128; off > 0; off >>= 1) {
        if (threadIdx.x < off) s[threadIdx.x] += s[threadIdx.x + off];
        __syncthreads();
    }
    if (threadIdx.x == 0) bsum[blockIdx.x] = s[0];
}

__global__ void k_scan_b(const int* __restrict__ bsum, int* __restrict__ boff) {
    __shared__ int s[512];
    int t = threadIdx.x;
    s[t] = (t < NB1) ? bsum[t] : 0;
    __syncthreads();
    for (int off = 1; off < 512; off <<= 1) {
        int v = (t >= off) ? s[t - off] : 0;
        __syncthreads();
        s[t] += v;
        __syncthreads();
    }
    if (t < NB1) boff[t] = (t == 0) ? 0 : s[t - 1];
}

__global__ void k_scan_c(const int* __restrict__ deg_in, const int* __restrict__ deg_out,
                         const int* __restrict__ boff, int* __restrict__ row_off,
                         int* __restrict__ cursor, float* __restrict__ nsrc,
                         float* __restrict__ ndst) {
    __shared__ int s[256];
    int t = threadIdx.x;
    int i = blockIdx.x * 256 + t;
    int d = (i < NN) ? deg_in[i] : 0;
    s[t] = d;
    __syncthreads();
    for (int off = 1; off < 256; off <<= 1) {
        int v = (t >= off) ? s[t - off] : 0;
        __syncthreads();
        s[t] += v;
        __syncthreads();
    }
    int excl = s[t] - d + boff[blockIdx.x];
    if (i < NN) {
        row_off[i] = excl;
        cursor[i]  = excl;
        ndst[i] = rsqrtf(fmaxf((float)d, 1.0f));
        nsrc[i] = rsqrtf(fmaxf((float)deg_out[i], 1.0f));
        if (i == NN - 1) row_off[NN] = excl + d;
    }
}

// ---------------- fast CSR 1: per-(bucket,group) histograms of dst AND src ----------------
__global__ __launch_bounds__(256) void k_hist2(const int* __restrict__ src,
                                               const int* __restrict__ dst,
                                               int* __restrict__ counts_d,
                                               int* __restrict__ counts_s) {
    __shared__ int hd[BBUK], hs[BBUK];
    for (int i = threadIdx.x; i < BBUK; i += 256) { hd[i] = 0; hs[i] = 0; }
    __syncthreads();
    const int g = blockIdx.x;
    const int e0 = g * CHUNK;
    for (int i = threadIdx.x; i < CHUNK; i += 256) {
        atomicAdd(&hd[dst[e0 + i] >> 9], 1);
        atomicAdd(&hs[src[e0 + i] >> 9], 1);
    }
    __syncthreads();
    for (int i = threadIdx.x; i < BBUK; i += 256) {
        counts_d[i * GBIN + g] = hd[i];
        counts_s[i * GBIN + g] = hs[i];
    }
}

// ---------------- fast CSR 2: fused exclusive scan of both counts arrays ----------------
__global__ void k_cs_a(const int* __restrict__ counts, int* __restrict__ csum) {
    __shared__ int s[256];
    int i = blockIdx.x * 256 + threadIdx.x;
    s[threadIdx.x] = counts[i];
    __syncthreads();
    for (int off = 128; off > 0; off >>= 1) {
        if (threadIdx.x < off) s[threadIdx.x] += s[threadIdx.x + off];
        __syncthreads();
    }
    if (threadIdx.x == 0) csum[blockIdx.x] = s[0];
}

__global__ void k_cs_b2(const int* __restrict__ csum, int* __restrict__ coff) {
    __shared__ int s[512];
    int t = threadIdx.x;
    int half = t >> 8, j = t & 255;
    s[t] = (j < NCB) ? csum[half * NCB + j] : 0;
    __syncthreads();
    for (int off = 1; off < 256; off <<= 1) {
        int v = (j >= off) ? s[t - off] : 0;
        __syncthreads();
        s[t] += v;
        __syncthreads();
    }
    if (j < NCB) coff[half * NCB + j] = (j == 0) ? 0 : s[t - 1];
}

__global__ void k_cs_c(int* __restrict__ counts, const int* __restrict__ coff) {
    __shared__ int s[256];
    int t = threadIdx.x;
    int i = blockIdx.x * 256 + t;
    int v = counts[i];
    s[t] = v;
    __syncthreads();
    for (int off = 1; off < 256; off <<= 1) {
        int u = (t >= off) ? s[t - off] : 0;
        __syncthreads();
        s[t] += u;
        __syncthreads();
    }
    counts[i] = s[t] - v + coff[blockIdx.x];
}

// ---------------- fast CSR 3: private-slice binning of dst-edges AND src-residues ----------------
__global__ __launch_bounds__(256) void k_binscatter2(const int* __restrict__ src,
                                                     const int* __restrict__ dst,
                                                     const int* __restrict__ counts_d,
                                                     const int* __restrict__ counts_s,
                                                     unsigned int* __restrict__ packed,
                                                     unsigned short* __restrict__ packed2) {
    __shared__ int curd[BBUK], curs[BBUK];
    const int g = blockIdx.x;
    for (int i = threadIdx.x; i < BBUK; i += 256) {
        curd[i] = counts_d[i * GBIN + g];
        curs[i] = counts_s[i * GBIN + g];
    }
    __syncthreads();
    const int e0 = g * CHUNK;
    for (int i = threadIdx.x; i < CHUNK; i += 256) {
        int s = src[e0 + i], d = dst[e0 + i];
        int pd = atomicAdd(&curd[d >> 9], 1);
        packed[pd] = ((unsigned)s << 9) | (unsigned)(d & 511);
        int ps = atomicAdd(&curs[s >> 9], 1);
        packed2[ps] = (unsigned short)(s & 511);
    }
}

// ---------------- fast CSR 4: per-bucket out-degree histogram -> nsrc directly ----------------
__global__ __launch_bounds__(256) void k_bdeg_out_nsrc(const int* __restrict__ counts_s,
                                                       const unsigned short* __restrict__ packed2,
                                                       float* __restrict__ nsrc) {
    __shared__ int h[512];
    const int b = blockIdx.x;
    const int n0 = b << 9;
    const int nlim = (NN - n0 < 512) ? (NN - n0) : 512;
    for (int j = threadIdx.x; j < 512; j += 256) h[j] = 0;
    __syncthreads();
    const int beg = counts_s[b * GBIN];
    const int end = (b + 1 < BBUK) ? counts_s[(b + 1) * GBIN] : NE;
    for (int i = beg + threadIdx.x; i < end; i += 256)
        atomicAdd(&h[packed2[i] & 511u], 1);
    __syncthreads();
    for (int j = threadIdx.x; j < nlim; j += 256)
        nsrc[n0 + j] = rsqrtf(fmaxf((float)h[j], 1.0f));
}

// ---------------- fast CSR 5 (fused): in-deg histogram + intra-bucket Blelloch scan
//                  + row_off/ndst write + within-bucket scatter, one kernel ----------------
// row_off[n] = counts_d[b*GBIN] + exclusive_scan(deg_in within bucket b)[n].
// Eliminates the node-level global scan (scan_a/scan_b/scan_c) and bucketC512.
__global__ __launch_bounds__(256) void k_bucket_all(const int* __restrict__ counts_d,
                                                    const unsigned int* __restrict__ packed,
                                                    int* __restrict__ row_off,
                                                    float* __restrict__ ndst,
                                                    int* __restrict__ srcs_sorted) {
    __shared__ int h[512];
    const int b = blockIdx.x;
    const int n0 = b << 9;
    const int nlim = (NN - n0 < 512) ? (NN - n0) : 512;
    const int t = threadIdx.x;
    for (int j = t; j < 512; j += 256) h[j] = 0;
    __syncthreads();
    const int beg = counts_d[b * GBIN];
    const int end = (b + 1 < BBUK) ? counts_d[(b + 1) * GBIN] : NE;
    // 1) in-degree histogram over this bucket's packed slice
    for (int i = beg + t; i < end; i += 256)
        atomicAdd(&h[packed[i] & 511u], 1);
    __syncthreads();
    const int degA = h[t], degB = h[t + 256];   // saved for ndst
    // 2) Blelloch exclusive scan of 512 elems (256 threads); first loop-iter
    //    barrier orders these reads before any scan write.
    int offset = 1;
    #pragma unroll
    for (int d = 256; d > 0; d >>= 1) {
        __syncthreads();
        if (t < d) {
            int ai = offset * (2 * t + 1) - 1;
            int bi = offset * (2 * t + 2) - 1;
            h[bi] += h[ai];
        }
        offset <<= 1;
    }
    __syncthreads();
    if (t == 0) h[511] = 0;
    #pragma unroll
    for (int d = 1; d < 512; d <<= 1) {
        offset >>= 1;
        __syncthreads();
        if (t < d) {
            int ai = offset * (2 * t + 1) - 1;
            int bi = offset * (2 * t + 2) - 1;
            int tmp = h[ai]; h[ai] = h[bi]; h[bi] += tmp;
        }
    }
    __syncthreads();
    // 3) row_off / ndst / cursor init
    const int r0 = beg + h[t];
    const int r1 = beg + h[t + 256];
    if (t < nlim) {
        row_off[n0 + t] = r0;
        ndst[n0 + t] = rsqrtf(fmaxf((float)degA, 1.0f));
    }
    if (t + 256 < nlim) {
        row_off[n0 + t + 256] = r1;
        ndst[n0 + t + 256] = rsqrtf(fmaxf((float)degB, 1.0f));
    }
    if (n0 + nlim == NN && t == 0) row_off[NN] = end;
    __syncthreads();
    h[t] = r0; h[t + 256] = r1;   // LDS cursors
    __syncthreads();
    // 4) within-bucket scatter (re-read is L2-hot)
    for (int i = beg + t; i < end; i += 256) {
        unsigned v = packed[i];
        int p = atomicAdd(&h[v & 511u], 1);
        srcs_sorted[p] = (int)(v >> 9);
    }
}

// ---------------- W1 -> bf16 fragment-ordered layout ----------------
__global__ void k_prepW(const void* __restrict__ W1, unsigned short* __restrict__ W1f,
                        const int* __restrict__ mode) {
    const bool f32 = (mode[0] != 0);
    for (int i = threadIdx.x; i < 1024; i += 256) {
        const int kcnt = i >> 6, lane = i & 63;
        const int kc = kcnt >> 2, nt = kcnt & 3;
        const int quad = lane >> 4, col = lane & 15;
        #pragma unroll
        for (int j = 0; j < 8; ++j) {
            const size_t idx = (size_t)(kc * 32 + quad * 8 + j) * NH + nt * 16 + col;
            W1f[(size_t)i * 8 + j] = f32 ? f2us_rn(((const float*)W1)[idx])
                                         : ((const unsigned short*)W1)[idx];
        }
    }
}

// ---------------- layer 1 GEMM (MFMA, both dtypes) ----------------
__global__ __launch_bounds__(256) void k_gemm1_mfma(
    const void* __restrict__ x, const unsigned short* __restrict__ W1f,
    const float* __restrict__ nsrc, unsigned short* __restrict__ h1,
    const int* __restrict__ mode)
{
    const bool f32 = (mode[0] != 0);
    const int tid = threadIdx.x;
    const int wave = tid >> 6, lane = tid & 63;
    const int col = lane & 15, quad = lane >> 4;

    short8v bfrag[16];
    #pragma unroll
    for (int f = 0; f < 16; ++f)
        bfrag[f] = *(const short8v*)(W1f + ((size_t)f * 64 + lane) * 8);

    const int base = blockIdx.x * 64 + wave * 16;
    int arow = base + col;
    if (arow > NN - 1) arow = NN - 1;

    short8v afrag[4];
    if (f32) {
        const float4* ap = (const float4*)((const float*)x + (size_t)arow * NF);
        #pragma unroll
        for (int kc = 0; kc < 4; ++kc) {
            float4 v0 = ap[kc * 8 + quad * 2];
            float4 v1 = ap[kc * 8 + quad * 2 + 1];
            short8v af;
            af[0] = (short)f2us_rn(v0.x); af[1] = (short)f2us_rn(v0.y);
            af[2] = (short)f2us_rn(v0.z); af[3] = (short)f2us_rn(v0.w);
            af[4] = (short)f2us_rn(v1.x); af[5] = (short)f2us_rn(v1.y);
            af[6] = (short)f2us_rn(v1.z); af[7] = (short)f2us_rn(v1.w);
            afrag[kc] = af;
        }
    } else {
        const uint4* ap = (const uint4*)((const unsigned short*)x + (size_t)arow * NF);
        #pragma unroll
        for (int kc = 0; kc < 4; ++kc) {
            uint4 v = ap[kc * 4 + quad];
            afrag[kc] = *reinterpret_cast<const short8v*>(&v);
        }
    }

    float4v acc[4];
    #pragma unroll
    for (int nt = 0; nt < 4; ++nt) acc[nt] = (float4v){0.f, 0.f, 0.f, 0.f};
    #pragma unroll
    for (int kc = 0; kc < 4; ++kc)
        #pragma unroll
        for (int nt = 0; nt < 4; ++nt)
            acc[nt] = __builtin_amdgcn_mfma_f32_16x16x32_bf16(afrag[kc], bfrag[kc * 4 + nt], acc[nt], 0, 0, 0);

    #pragma unroll
    for (int reg = 0; reg < 4; ++reg) {
        const int row = base + quad * 4 + reg;
        if (row < NN) {
            const float ns = nsrc[row];
            unsigned short* hp = h1 + (size_t)row * NH + col;
            hp[0]  = f2us_rn(acc[0][reg] * ns);
            hp[16] = f2us_rn(acc[1][reg] * ns);
            hp[32] = f2us_rn(acc[2][reg] * ns);
            hp[48] = f2us_rn(acc[3][reg] * ns);
        }
    }
}

// ---------------- fused layer-1 aggregation + relu + W2 GEMM ----------------
// R10 configuration (measured 60.6 us): 4 slots x 16 feature-quads, dwordx2,
// 2-deep. R11's 8-slot/dwordx4 variant measured 70.3 us - REVERTED.
__global__ __launch_bounds__(256) void k_agg1csr(
    const int* __restrict__ row_off, const int* __restrict__ srcs,
    const unsigned short* __restrict__ h1, const float* __restrict__ ndst,
    const float* __restrict__ nsrc, const void* __restrict__ b1,
    const void* __restrict__ W2, const int* __restrict__ mode,
    unsigned short* __restrict__ h2)
{
    const bool f32 = (mode[0] != 0);
    const int lane = threadIdx.x & 63;
    const int q  = lane >> 4;    // edge slot / column subset
    const int li = lane & 15;    // feature quad: feats 4li..4li+3

    const float bias0 = ldf(b1, 4*li+0, f32), bias1 = ldf(b1, 4*li+1, f32);
    const float bias2 = ldf(b1, 4*li+2, f32), bias3 = ldf(b1, 4*li+3, f32);
    float w2[4][4];
    #pragma unroll
    for (int j = 0; j < 4; ++j)
        #pragma unroll
        for (int m = 0; m < 4; ++m)
            w2[j][m] = ldf(W2, (size_t)(4*li+j)*NC + (q + 4*m), f32);

    const int wid = (blockIdx.x * blockDim.x + threadIdx.x) >> 6;
    const int nw  = (gridDim.x * blockDim.x) >> 6;

    for (int row = wid; row < NN; row += nw) {
        const int beg = row_off[row], end = row_off[row + 1];
        float ax = 0.f, ay = 0.f, az = 0.f, aw = 0.f;
        float bx = 0.f, by = 0.f, bz = 0.f, bw = 0.f;
        int i = beg + q;
        int s0 = (i     < end) ? srcs[i]     : 0;
        int s1 = (i + 4 < end) ? srcs[i + 4] : 0;
        while (i + 4 < end) {
            uint2 v0 = *(const uint2*)(h1 + (size_t)s0 * NH + 4*li);
            uint2 v1 = *(const uint2*)(h1 + (size_t)s1 * NH + 4*li);
            const int inext = i + 8;
            s0 = (inext     < end) ? srcs[inext]     : 0;
            s1 = (inext + 4 < end) ? srcs[inext + 4] : 0;
            ax += us2f((unsigned short)(v0.x & 0xFFFF));
            ay += us2f((unsigned short)(v0.x >> 16));
            az += us2f((unsigned short)(v0.y & 0xFFFF));
            aw += us2f((unsigned short)(v0.y >> 16));
            bx += us2f((unsigned short)(v1.x & 0xFFFF));
            by += us2f((unsigned short)(v1.x >> 16));
            bz += us2f((unsigned short)(v1.y & 0xFFFF));
            bw += us2f((unsigned short)(v1.y >> 16));
            i = inext;
        }
        if (i < end) {
            uint2 v0 = *(const uint2*)(h1 + (size_t)s0 * NH + 4*li);
            ax += us2f((unsigned short)(v0.x & 0xFFFF));
            ay += us2f((unsigned short)(v0.x >> 16));
            az += us2f((unsigned short)(v0.y & 0xFFFF));
            aw += us2f((unsigned short)(v0.y >> 16));
        }
        ax += bx; ay += by; az += bz; aw += bw;
        ax += __shfl_xor(ax, 16); ay += __shfl_xor(ay, 16);
        az += __shfl_xor(az, 16); aw += __shfl_xor(aw, 16);
        ax += __shfl_xor(ax, 32); ay += __shfl_xor(ay, 32);
        az += __shfl_xor(az, 32); aw += __shfl_xor(aw, 32);

        const float nd = ndst[row];
        const float t0 = fmaxf(fmaf(ax, nd, bias0), 0.f);
        const float t1 = fmaxf(fmaf(ay, nd, bias1), 0.f);
        const float t2 = fmaxf(fmaf(az, nd, bias2), 0.f);
        const float t3 = fmaxf(fmaf(aw, nd, bias3), 0.f);

        float p0 = fmaf(t0,w2[0][0],fmaf(t1,w2[1][0],fmaf(t2,w2[2][0],t3*w2[3][0])));
        float p1 = fmaf(t0,w2[0][1],fmaf(t1,w2[1][1],fmaf(t2,w2[2][1],t3*w2[3][1])));
        float p2 = fmaf(t0,w2[0][2],fmaf(t1,w2[1][2],fmaf(t2,w2[2][2],t3*w2[3][2])));
        float p3 = fmaf(t0,w2[0][3],fmaf(t1,w2[1][3],fmaf(t2,w2[2][3],t3*w2[3][3])));
        #pragma unroll
        for (int off = 1; off <= 8; off <<= 1) {
            p0 += __shfl_xor(p0, off);
            p1 += __shfl_xor(p1, off);
            p2 += __shfl_xor(p2, off);
            p3 += __shfl_xor(p3, off);
        }
        if (li < 4) {
            float v = (li == 0) ? p0 : (li == 1) ? p1 : (li == 2) ? p2 : p3;
            h2[(size_t)row * NC + q + 4*li] = f2us_rn(v * nsrc[row]);
        }
    }
}

// ---------------- fused layer-2 aggregation + bias + log_softmax ----------------
// R11 configuration (kept: measured ~3 us better than R10's).
__global__ __launch_bounds__(256) void k_out(
    const int* __restrict__ row_off, const int* __restrict__ srcs,
    const unsigned short* __restrict__ h2, const float* __restrict__ ndst,
    const void* __restrict__ b2, const int* __restrict__ mode,
    void* __restrict__ out)
{
    const bool f32 = (mode[0] != 0);
    const int lane = threadIdx.x & 63;
    const int q  = lane >> 3;
    const int li = lane & 7;
    const float b2v0 = ldf(b2, 2*li,   f32);
    const float b2v1 = ldf(b2, 2*li+1, f32);

    const int wid = (blockIdx.x * blockDim.x + threadIdx.x) >> 6;
    const int nw  = (gridDim.x * blockDim.x) >> 6;

    for (int r = wid; r < NN; r += nw) {
        const int beg = row_off[r], end = row_off[r + 1];
        float a0 = 0.f, a1 = 0.f, c0 = 0.f, c1 = 0.f;
        int i = beg + q;
        int s0 = (i     < end) ? srcs[i]     : 0;
        int s1 = (i + 8 < end) ? srcs[i + 8] : 0;
        while (i + 8 < end) {
            unsigned u0 = *(const unsigned*)(h2 + (size_t)s0 * NC + 2*li);
            unsigned u1 = *(const unsigned*)(h2 + (size_t)s1 * NC + 2*li);
            const int inext = i + 16;
            s0 = (inext     < end) ? srcs[inext]     : 0;
            s1 = (inext + 8 < end) ? srcs[inext + 8] : 0;
            a0 += us2f((unsigned short)(u0 & 0xFFFF));
            a1 += us2f((unsigned short)(u0 >> 16));
            c0 += us2f((unsigned short)(u1 & 0xFFFF));
            c1 += us2f((unsigned short)(u1 >> 16));
            i = inext;
        }
        if (i < end) {
            unsigned u0 = *(const unsigned*)(h2 + (size_t)s0 * NC + 2*li);
            a0 += us2f((unsigned short)(u0 & 0xFFFF));
            a1 += us2f((unsigned short)(u0 >> 16));
        }
        a0 += c0; a1 += c1;
        #pragma unroll
        for (int off = 8; off <= 32; off <<= 1) {
            a0 += __shfl_xor(a0, off);
            a1 += __shfl_xor(a1, off);
        }
        const float nd = ndst[r];
        float v0 = fmaf(a0, nd, b2v0);
        float v1 = fmaf(a1, nd, b2v1);
        float m = fmaxf(v0, v1);
        #pragma unroll
        for (int off = 1; off <= 4; off <<= 1) m = fmaxf(m, __shfl_xor(m, off));
        float sm = __expf(v0 - m) + __expf(v1 - m);
        #pragma unroll
        for (int off = 1; off <= 4; off <<= 1) sm += __shfl_xor(sm, off);
        const float lsm = __logf(sm);
        const float r0 = v0 - m - lsm, r1 = v1 - m - lsm;
        if (q == 0) {
            if (f32) {
                float2 o; o.x = r0; o.y = r1;
                *(float2*)((float*)out + (size_t)r * NC + 2*li) = o;
            } else {
                unsigned o = ((unsigned)f2us_rn(r1) << 16) | (unsigned)f2us_rn(r0);
                *(unsigned*)((unsigned short*)out + (size_t)r * NC + 2*li) = o;
            }
        }
    }
}

extern "C" void kernel_launch(void* const* d_in, const int* in_sizes, int n_in,
                              void* d_out, int out_size, void* d_ws, size_t ws_size,
                              hipStream_t stream) {
    const void* x  = d_in[0];
    const int* src = (const int*)d_in[1];
    const int* dst = (const int*)d_in[2];
    const void* W1 = d_in[3];
    const void* b1 = d_in[4];
    const void* W2 = d_in[5];
    const void* b2 = d_in[6];

    // ---- workspace layout ----
    char* ws = (char*)d_ws;
    const size_t O_MODE = 0;                     // 1 KB
    const size_t O_W1F  = 1024;                  // fragment-ordered W1 (bf16), 16384 B
    const size_t O_CNT  = O_W1F + 16384;         // counts_d + counts_s = 401408
    const size_t O_CS   = O_CNT  + 401408;       // csum 2048 + coff 2048
    const size_t O_DEG  = O_CS   + 4096;         // 800000 (fallback only)
    const size_t O_NSRC = O_DEG  + 800000;
    const size_t O_NDST = O_NSRC + 400000;
    const size_t O_ROW  = O_NDST + 400000;       // (NN+1)*4 padded
    const size_t O_CUR  = O_ROW  + 400128;       // fallback per-node cursors
    const size_t O_BS   = O_CUR  + 400128;       // bsum 2048 + boff 2048 (fallback)
    const size_t O_SRCS = O_BS   + 4096;         // NE*4
    const size_t O_H2   = O_SRCS + 6400000;      // NN*NC*2 bf16
    const size_t O_H1   = O_H2   + 3200000;      // NN*NH*2 bf16 = 12800000
    // packed (NE*4) + packed2 (NE*2) alias into h1 (dead before gemm1)
    const size_t NEED = O_H1 + 12800000;         // ~25.2 MB
    const bool fast_csr = ws_size >= NEED;

    int*   mode     = (int*)(ws + O_MODE);
    unsigned short* W1f = (unsigned short*)(ws + O_W1F);
    int*   counts_d = (int*)(ws + O_CNT);
    int*   counts_s = counts_d + BBUK * GBIN;
    int*   csum     = (int*)(ws + O_CS);
    int*   coff     = (int*)(ws + O_CS + 2048);
    int*   deg_out  = (int*)(ws + O_DEG);
    int*   deg_in   = deg_out + NN;
    float* nsrc     = (float*)(ws + O_NSRC);
    float* ndst     = (float*)(ws + O_NDST);
    int*   row_off  = (int*)(ws + O_ROW);
    int*   cursor   = (int*)(ws + O_CUR);
    int*   bsum     = (int*)(ws + O_BS);
    int*   boff     = (int*)(ws + O_BS + 2048);
    int*   srcs_s   = (int*)(ws + O_SRCS);
    unsigned short* h2 = (unsigned short*)(ws + O_H2);
    unsigned short* h1 = (unsigned short*)(ws + O_H1);
    unsigned int*   packed  = (unsigned int*)(ws + O_H1);
    unsigned short* packed2 = (unsigned short*)(ws + O_H1 + 6400000);

    k_sniff<<<1, 256, 0, stream>>>((const unsigned short*)x, mode);
    k_prepW<<<1, 256, 0, stream>>>(W1, W1f, mode);
    if (fast_csr) {
        k_hist2<<<GBIN, 256, 0, stream>>>(src, dst, counts_d, counts_s);
        k_cs_a<<<2 * NCB, 256, 0, stream>>>(counts_d, csum);
        k_cs_b2<<<1, 512, 0, stream>>>(csum, coff);
        k_cs_c<<<2 * NCB, 256, 0, stream>>>(counts_d, coff);
        k_binscatter2<<<GBIN, 256, 0, stream>>>(src, dst, counts_d, counts_s, packed, packed2);
        k_bdeg_out_nsrc<<<BBUK, 256, 0, stream>>>(counts_s, packed2, nsrc);
        k_bucket_all<<<BBUK, 256, 0, stream>>>(counts_d, packed, row_off, ndst, srcs_s);
    } else {
        hipMemsetAsync(deg_out, 0, 2 * (size_t)NN * sizeof(int), stream);
        k_deg<<<(NE / 4 + 255) / 256, 256, 0, stream>>>((const int4*)src, (const int4*)dst, deg_out, deg_in);
        k_scan_a<<<NB1, 256, 0, stream>>>(deg_in, bsum);
        k_scan_b<<<1, 512, 0, stream>>>(bsum, boff);
        k_scan_c<<<NB1, 256, 0, stream>>>(deg_in, deg_out, boff, row_off, cursor, nsrc, ndst);
        k_scatter<<<(NE + 255) / 256, 256, 0, stream>>>(src, dst, cursor, srcs_s);
    }
    k_gemm1_mfma<<<NGRP, 256, 0, stream>>>(x, W1f, nsrc, h1, mode);
    k_agg1csr<<<2048, 256, 0, stream>>>(row_off, srcs_s, h1, ndst, nsrc, b1, W2, mode, h2);
    k_out<<<2048, 256, 0, stream>>>(row_off, srcs_s, h2, ndst, b2, mode, d_out);
}